// Round 1
// 1791.472 us; speedup vs baseline: 1.1859x; 1.1859x over previous
//
#include <hip/hip_runtime.h>

// LSTM net: linear1(20->50) -> 3x LSTMCell(50) with reference's buggy c-flow
//   -> linear2(50->8).  B=512, T=1024.
//
// 256 blocks x 768 threads, 1 block/CU (2 batch elems per block).
// Wave-specialized 3-stage pipeline over timesteps: at step s, L1 gates
// compute t=s, L2 t=s-1, L3 t=s-2, out-proj t=s-3.
//
// This revision vs previous:
//  * gate path is BRANCH-FREE (per-lane LDS offsets via selects) so the
//    layer-mixed waves (3 and 6) issue ONE path: 10 gate wave-paths, not 12.
//  * all dot products use v_pk_fma_f32 (2 FMAs/instr) via inline asm with
//    "v" constraints, which also forces the 52 weight-pairs (104 VGPRs)
//    into arch VGPRs instead of AGPR+accvgpr_read churn (prev: VGPR=72).
//  * h/x state stored batch-UNPACKED [2][KP=52] so packed fma needs no
//    repacking: f32x4 LDS load = 4 consecutive k of one batch.
//  * out-proj reads h3 as 13x ds_read_b128 instead of 50 scalar reads.

#define T_SEQ 1024
#define HID   50
#define IN_DIM 20
#define OUT_DIM 8
#define KP   52     // k padded to multiple of 4 (pad elems stay 0)
#define KP2  104    // 2 batches * KP

typedef float f32x2 __attribute__((ext_vector_type(2)));
typedef float f32x4 __attribute__((ext_vector_type(4)));

// d = a*b + d, per 32-bit lane of the 64-bit pair (2 FMAs per issue)
__device__ __forceinline__ void pkfma(f32x2& d, f32x2 a, f32x2 b) {
    asm("v_pk_fma_f32 %0, %1, %2, %0" : "+v"(d) : "v"(a), "v"(b));
}

__device__ __forceinline__ float sigm(float x) {
    return __builtin_amdgcn_rcpf(1.0f + __expf(-x));
}
__device__ __forceinline__ float tanh_f(float x) {
    return fmaf(2.0f, sigm(2.0f * x), -1.0f);
}

// LDS float layout (all 16B-aligned bases; batch-unpacked vectors)
#define X0 0      // xbuf [3 slots][2 b][KP] = 312 floats, ring slot = t%3
#define H1 312    // h1   [2 slots][2 b][KP] = 208
#define H2 520    // h2   [2][2][KP]
#define H3 728    // h3   [2][2][KP]
#define GB 936    // gbuf f32x2[600] = {b0,b1} activated gates, 1200 floats
#define SMSZ 2136

__global__ __launch_bounds__(768, 3) void lstm_net_kernel(
    const float* __restrict__ x,
    const float* __restrict__ W1,   const float* __restrict__ b1,
    const float* __restrict__ Wih1, const float* __restrict__ Whh1,
    const float* __restrict__ bih1, const float* __restrict__ bhh1,
    const float* __restrict__ Wih2, const float* __restrict__ Whh2,
    const float* __restrict__ bih2, const float* __restrict__ bhh2,
    const float* __restrict__ Wih3, const float* __restrict__ Whh3,
    const float* __restrict__ bih3, const float* __restrict__ bhh3,
    const float* __restrict__ W2,   const float* __restrict__ b2,
    float* __restrict__ out)
{
    __shared__ __align__(16) float sm[SMSZ];

    const int tid = threadIdx.x;
    const int b0  = blockIdx.x * 2;

    // zero LDS (initial h/c = 0; also the KP pads must stay 0)
    for (int i = tid; i < SMSZ; i += 768) sm[i] = 0.f;
    __syncthreads();

    // ---- role setup; wp[] shared across disjoint roles to cap VGPRs ----
    f32x2 wp[52];                        // weight pairs (104 VGPRs)
    float biasr = 0.f;
    int   lyr = 0, g = 0;
    float a2 = 1.f, cc = 0.f;            // activation: a2*sigm(a2*x)+cc
    int   ob = 0, ok = 0;                // out-proj role
    int   pb = 0, pj = 0;                // prefetch role
    f32x2 c1 = {0.f, 0.f};               // L1 cell state (threads 0-49)
    float xstage = 0.f;

    if (tid < 600) {                     // gate threads
        lyr = tid / 200; g = tid % 200;
        const float* Wih = (lyr == 0) ? Wih1 : (lyr == 1 ? Wih2 : Wih3);
        const float* Whh = (lyr == 0) ? Whh1 : (lyr == 1 ? Whh2 : Whh3);
        const float* bi  = (lyr == 0) ? bih1 : (lyr == 1 ? bih2 : bih3);
        const float* bh  = (lyr == 0) ? bhh1 : (lyr == 1 ? bhh2 : bhh3);
        #pragma unroll
        for (int j = 0; j < 25; j++) {
            wp[j].x      = Wih[g * 50 + 2 * j];
            wp[j].y      = Wih[g * 50 + 2 * j + 1];
            wp[26 + j].x = Whh[g * 50 + 2 * j];
            wp[26 + j].y = Whh[g * 50 + 2 * j + 1];
        }
        wp[25] = (f32x2){0.f, 0.f};
        wp[51] = (f32x2){0.f, 0.f};
        biasr = bi[g] + bh[g];
        if (g >= 100 && g < 150) { a2 = 2.f; cc = -1.f; }   // 'g' gate: tanh
    } else if (tid >= 640 && tid < 656) {        // out-proj: 8 outs x 2 batch
        int idx = tid - 640; ob = idx >> 3; ok = idx & 7;
        #pragma unroll
        for (int j = 0; j < 25; j++) {
            wp[j].x = W2[ok * 50 + 2 * j];
            wp[j].y = W2[ok * 50 + 2 * j + 1];
        }
        wp[25] = (f32x2){0.f, 0.f};
        biasr = b2[ok];
    } else if (tid >= 656 && tid < 756) {        // linear1 prefetch: 50 j x 2 b
        int idx = tid - 656; pb = idx / 50; pj = idx % 50;
        #pragma unroll
        for (int j = 0; j < 10; j++) {
            wp[j].x = W1[pj * 20 + 2 * j];
            wp[j].y = W1[pj * 20 + 2 * j + 1];
        }
        biasr = b1[pj];
        // prologue: hid(0) -> slot0, hid(1) -> slot1
        const f32x4* xv = (const f32x4*)(x + ((size_t)(b0 + pb)) * T_SEQ * IN_DIM);
        f32x2 s0 = {0.f, 0.f}, s1 = {0.f, 0.f};
        #pragma unroll
        for (int k = 0; k < 5; k++) {
            f32x4 u = xv[k];
            pkfma(s0, wp[2 * k], u.lo);
            pkfma(s0, wp[2 * k + 1], u.hi);
        }
        #pragma unroll
        for (int k = 0; k < 5; k++) {
            f32x4 u = xv[5 + k];
            pkfma(s1, wp[2 * k], u.lo);
            pkfma(s1, wp[2 * k + 1], u.hi);
        }
        sm[X0 + 0 * KP2 + pb * KP + pj] = s0.x + s0.y + biasr;
        sm[X0 + 1 * KP2 + pb * KP + pj] = s1.x + s1.y + biasr;
    }
    __syncthreads();

    for (int s = 0; s < T_SEQ + 3; ++s) {
        const int p = s & 1, pm = p ^ 1, q3 = s % 3;

        // ================= phase A =================
        if (tid < 600) {
            // branch-free per-lane operand bases (selects, not branches)
            const int offA = (lyr == 0) ? (X0 + q3 * KP2)
                           : ((lyr == 1) ? (H1 + pm * KP2) : (H2 + p * KP2));
            const int offB = (lyr == 0) ? (H1 + pm * KP2)
                           : ((lyr == 1) ? (H2 + p * KP2) : (H3 + pm * KP2));
            const f32x4* A0 = (const f32x4*)(sm + offA);        // batch0
            const f32x4* A1 = (const f32x4*)(sm + offA + KP);   // batch1
            const f32x4* B0 = (const f32x4*)(sm + offB);
            const f32x4* B1 = (const f32x4*)(sm + offB + KP);
            f32x2 ac0 = {0.f, 0.f}, ac1 = {0.f, 0.f};
            f32x2 ac2 = {0.f, 0.f}, ac3 = {0.f, 0.f};
            #pragma unroll
            for (int k = 0; k < 13; k++) {
                f32x4 u0 = A0[k], u1 = A1[k];
                pkfma(ac0, wp[2 * k],     u0.lo);
                pkfma(ac1, wp[2 * k + 1], u0.hi);
                pkfma(ac2, wp[2 * k],     u1.lo);
                pkfma(ac3, wp[2 * k + 1], u1.hi);
            }
            #pragma unroll
            for (int k = 0; k < 13; k++) {
                f32x4 u0 = B0[k], u1 = B1[k];
                pkfma(ac0, wp[26 + 2 * k],     u0.lo);
                pkfma(ac1, wp[26 + 2 * k + 1], u0.hi);
                pkfma(ac2, wp[26 + 2 * k],     u1.lo);
                pkfma(ac3, wp[26 + 2 * k + 1], u1.hi);
            }
            const float px_ = ac0.x + ac0.y + ac1.x + ac1.y + biasr;
            const float py_ = ac2.x + ac2.y + ac3.x + ac3.y + biasr;
            f32x2 r;
            r.x = fmaf(a2, sigm(a2 * px_), cc);
            r.y = fmaf(a2, sigm(a2 * py_), cc);
            ((f32x2*)(sm + GB))[lyr * 200 + g] = r;   // gbuf garbage outside
                                                      // valid t is never read
        } else if (tid >= 640 && tid < 656) {          // out(t = s-3)
            if (s >= 3) {
                const int t = s - 3;
                const f32x4* hv = (const f32x4*)(sm + H3 + pm * KP2 + ob * KP);
                f32x2 ac = {0.f, 0.f}, acb = {0.f, 0.f};
                #pragma unroll
                for (int k = 0; k < 13; k++) {
                    f32x4 u = hv[k];
                    pkfma(ac,  wp[2 * k],     u.lo);
                    pkfma(acb, wp[2 * k + 1], u.hi);
                }
                out[((size_t)(b0 + ob) * T_SEQ + t) * OUT_DIM + ok]
                    = ac.x + ac.y + acb.x + acb.y + biasr;
            }
        } else if (tid >= 656 && tid < 756) {          // hid(s+2) load+dot
            if (s + 2 < T_SEQ) {
                const f32x4* xv = (const f32x4*)
                    (x + (((size_t)(b0 + pb)) * T_SEQ + (s + 2)) * IN_DIM);
                f32x2 ac = {0.f, 0.f};
                #pragma unroll
                for (int k = 0; k < 5; k++) {
                    f32x4 u = xv[k];
                    pkfma(ac, wp[2 * k],     u.lo);
                    pkfma(ac, wp[2 * k + 1], u.hi);
                }
                xstage = ac.x + ac.y + biasr;
            }
        }
        __syncthreads();

        // ================= phase B (combines) =================
        if (tid < 50) {                                // L1 combine, t = s
            if (s < T_SEQ) {
                const f32x2* gb = (const f32x2*)(sm + GB);
                f32x2 gi = gb[tid],       gf = gb[50 + tid];
                f32x2 gg = gb[100 + tid], go = gb[150 + tid];
                c1.x = fmaf(gf.x, c1.x, gi.x * gg.x);
                c1.y = fmaf(gf.y, c1.y, gi.y * gg.y);
                sm[H1 + p * KP2 + tid]      = go.x * tanh_f(c1.x);
                sm[H1 + p * KP2 + KP + tid] = go.y * tanh_f(c1.y);
            }
        } else if (tid >= 64 && tid < 114) {           // L3 then L2 combine
            const int j = tid - 64;
            const f32x2* gb = (const f32x2*)(sm + GB);
            f32x2 cn3 = {0.f, 0.f};                    // c from cell3 (c3==0)
            if (s >= 2 && s <= T_SEQ + 1) {            // L3, t3 = s-2
                f32x2 gi = gb[400 + j], gg = gb[500 + j], go = gb[550 + j];
                cn3.x = gi.x * gg.x;
                cn3.y = gi.y * gg.y;
                sm[H3 + p * KP2 + j]      = go.x * tanh_f(cn3.x);
                sm[H3 + p * KP2 + KP + j] = go.y * tanh_f(cn3.y);
            }
            if (s >= 1 && s <= T_SEQ) {                // L2, t2 = s-1
                f32x2 gi = gb[200 + j], gf = gb[250 + j];
                f32x2 gg = gb[300 + j], go = gb[350 + j];
                f32x2 c2n;
                c2n.x = fmaf(gf.x, cn3.x, gi.x * gg.x);
                c2n.y = fmaf(gf.y, cn3.y, gi.y * gg.y);
                sm[H2 + pm * KP2 + j]      = go.x * tanh_f(c2n.x);
                sm[H2 + pm * KP2 + KP + j] = go.y * tanh_f(c2n.y);
            }
        } else if (tid >= 656 && tid < 756) {          // commit hid(s+2)
            if (s + 2 < T_SEQ) {
                sm[X0 + ((s + 2) % 3) * KP2 + pb * KP + pj] = xstage;
            }
        }
        __syncthreads();
    }
}

extern "C" void kernel_launch(void* const* d_in, const int* in_sizes, int n_in,
                              void* d_out, int out_size, void* d_ws, size_t ws_size,
                              hipStream_t stream) {
    const float* x    = (const float*)d_in[0];
    const float* W1   = (const float*)d_in[1];
    const float* b1   = (const float*)d_in[2];
    const float* Wih1 = (const float*)d_in[3];
    const float* Whh1 = (const float*)d_in[4];
    const float* bih1 = (const float*)d_in[5];
    const float* bhh1 = (const float*)d_in[6];
    const float* Wih2 = (const float*)d_in[7];
    const float* Whh2 = (const float*)d_in[8];
    const float* bih2 = (const float*)d_in[9];
    const float* bhh2 = (const float*)d_in[10];
    const float* Wih3 = (const float*)d_in[11];
    const float* Whh3 = (const float*)d_in[12];
    const float* bih3 = (const float*)d_in[13];
    const float* bhh3 = (const float*)d_in[14];
    const float* W2   = (const float*)d_in[15];
    const float* b2   = (const float*)d_in[16];
    float* out = (float*)d_out;

    dim3 grid(256), block(768);   // 512 batch / 2 per block; 12 waves/block
    lstm_net_kernel<<<grid, block, 0, stream>>>(
        x, W1, b1, Wih1, Whh1, bih1, bhh1, Wih2, Whh2, bih2, bhh2,
        Wih3, Whh3, bih3, bhh3, W2, b2, out);
}

// Round 2
// 1739.243 us; speedup vs baseline: 1.2215x; 1.0300x over previous
//
#include <hip/hip_runtime.h>

// LSTM net: linear1(20->50) -> 3x LSTMCell(50) with reference's buggy c-flow
//   -> linear2(50->8).  B=512, T=1024.
//
// 256 blocks x 768 threads, 1 block/CU (2 batch elems per block).
// SINGLE-BARRIER pipeline: gate compute AND combine fused per step via
// in-wave ds_swizzle reduction (no gbuf, no phase B).
//
// Lane map (per block):
//   tid   0-399 : L2+L3 gate groups of 8: [i2,g2,f2,o2, i3,g3,o3, idle]
//                 (f3 dropped: c3==0 so f3*c3 never contributes)
//   tid 400-599 : L1 gate quads: [i,g,f,o]
//   tid 640-655 : out-proj (8 outs x 2 batch)
//   tid 704-753 : linear1 prefetch (50 j, both batches)
// Per step s: L1 t=s, L2 t=s-1, L3 t=s-2 (cn3 -> L2 same step via xor4),
//             out t=s-3, prefetch commits hid(s+2), computes hid(s+3).

#define T_SEQ 1024
#define HID   50
#define IN_DIM 20
#define OUT_DIM 8
#define KP   52     // k padded to multiple of 4
#define KP2  104    // 2 batches * KP

// LDS float offsets
#define H1 312      // xbuf [3][2][KP] = 312 floats at 0
#define H2 520      // h1 [2][2][KP] = 208
#define H3 728
#define SMSZ 936

typedef float f32x2 __attribute__((ext_vector_type(2)));
typedef float f32x4 __attribute__((ext_vector_type(4)));

__device__ __forceinline__ void pkfma(f32x2& d, f32x2 a, f32x2 b) {
    asm("v_pk_fma_f32 %0, %1, %2, %0" : "+v"(d) : "v"(a), "v"(b));
}
__device__ __forceinline__ float sigm(float x) {
    return __builtin_amdgcn_rcpf(1.0f + __expf(-x));
}
__device__ __forceinline__ float tanh_f(float x) {
    return fmaf(2.0f, sigm(2.0f * x), -1.0f);
}
// in-wave lane exchange; IMM: 0x80B1 = quad_perm xor1, 0x804E = quad_perm xor2,
// 0x101F = bit-mode xor4 (groups never cross the 32-lane bit-mode boundary)
template <int IMM>
__device__ __forceinline__ f32x2 swz2(f32x2 v) {
    f32x2 r;
    r.x = __int_as_float(__builtin_amdgcn_ds_swizzle(__float_as_int(v.x), IMM));
    r.y = __int_as_float(__builtin_amdgcn_ds_swizzle(__float_as_int(v.y), IMM));
    return r;
}

__global__ __launch_bounds__(768, 3) void lstm_net_kernel(
    const float* __restrict__ x,
    const float* __restrict__ W1,   const float* __restrict__ b1,
    const float* __restrict__ Wih1, const float* __restrict__ Whh1,
    const float* __restrict__ bih1, const float* __restrict__ bhh1,
    const float* __restrict__ Wih2, const float* __restrict__ Whh2,
    const float* __restrict__ bih2, const float* __restrict__ bhh2,
    const float* __restrict__ Wih3, const float* __restrict__ Whh3,
    const float* __restrict__ bih3, const float* __restrict__ bhh3,
    const float* __restrict__ W2,   const float* __restrict__ b2,
    float* __restrict__ out)
{
    __shared__ __align__(16) float sm[SMSZ];

    const int tid = threadIdx.x;
    const int b0  = blockIdx.x * 2;

    // zero LDS (initial h state = 0; pads multiply by zeroed wp[25]/wp[51])
    for (int i = tid; i < SMSZ; i += 768) sm[i] = 0.f;
    __syncthreads();

    // ---- role setup; wp[] shared across disjoint roles ----
    f32x2 wp[52];
    float biasr = 0.f;
    float a2 = 1.f, cc = 0.f;            // activation: a2*sigm(a2*x)+cc
    int   dly = 0, cA = 0, cB = 1;       // pipeline delay; operand selectors
    int   comb = 0, j = 0;               // combine role + output index
    bool  alive = true;
    int   ob = 0, ok = 0, pj = 0;        // out-proj / prefetch params
    f32x2 c1  = {0.f, 0.f};              // L1 cell state (comb==1 lanes)
    f32x2 xst = {0.f, 0.f};              // prefetch staging

    if (tid < 600) {
        const float *Wih, *Whh, *bi, *bh;
        int row, r;
        if (tid < 400) {                 // L2+L3 groups of 8
            const int grp = tid >> 3;  r = tid & 7;  j = grp;
            if (r < 4) {                 // L2 roles [i2,g2,f2,o2]
                dly = 1; cA = 1; cB = 2;
                Wih = Wih2; Whh = Whh2; bi = bih2; bh = bhh2;
                row = (r == 0) ? grp : (r == 1) ? 100 + grp
                    : (r == 2) ? 50 + grp : 150 + grp;
                if (r == 1) { a2 = 2.f; cc = -1.f; }
                if (r == 2) comb = 2;
            } else {                     // L3 roles [i3,g3,o3,idle]
                const int rr = r - 4;
                dly = 2; cA = 2; cB = 3;
                Wih = Wih3; Whh = Whh3; bi = bih3; bh = bhh3;
                row = (rr == 0) ? grp : (rr == 1) ? 100 + grp : 150 + grp;
                if (rr == 1) { a2 = 2.f; cc = -1.f; }
                if (rr == 2) comb = 3;
                alive = (r != 7);
            }
        } else {                         // L1 quads [i,g,f,o]
            const int q = (tid - 400) >> 2;  r = tid & 3;  j = q;
            dly = 0; cA = 0; cB = 1;
            Wih = Wih1; Whh = Whh1; bi = bih1; bh = bhh1;
            row = (r == 0) ? q : (r == 1) ? 100 + q
                : (r == 2) ? 50 + q : 150 + q;
            if (r == 1) { a2 = 2.f; cc = -1.f; }
            if (r == 2) comb = 1;
        }
        #pragma unroll
        for (int k = 0; k < 25; k++) {
            wp[k].x      = Wih[row * 50 + 2 * k];
            wp[k].y      = Wih[row * 50 + 2 * k + 1];
            wp[26 + k].x = Whh[row * 50 + 2 * k];
            wp[26 + k].y = Whh[row * 50 + 2 * k + 1];
        }
        wp[25] = (f32x2){0.f, 0.f};
        wp[51] = (f32x2){0.f, 0.f};
        biasr = bi[row] + bh[row];
    } else if (tid >= 640 && tid < 656) {          // out-proj
        const int idx = tid - 640; ob = idx >> 3; ok = idx & 7;
        #pragma unroll
        for (int k = 0; k < 25; k++) {
            wp[k].x = W2[ok * 50 + 2 * k];
            wp[k].y = W2[ok * 50 + 2 * k + 1];
        }
        wp[25] = (f32x2){0.f, 0.f};
        biasr = b2[ok];
    } else if (tid >= 704 && tid < 754) {          // linear1 prefetch
        pj = tid - 704;
        #pragma unroll
        for (int k = 0; k < 10; k++) {
            wp[k].x = W1[pj * 20 + 2 * k];
            wp[k].y = W1[pj * 20 + 2 * k + 1];
        }
        biasr = b1[pj];
        // prologue: hid(0)->slot0, hid(1)->slot1, hid(2)->xst
        #pragma unroll
        for (int t = 0; t < 3; ++t) {
            const f32x4* xv0 = (const f32x4*)(x + ((size_t)b0 * T_SEQ + t) * IN_DIM);
            const f32x4* xv1 = (const f32x4*)(x + ((size_t)(b0 + 1) * T_SEQ + t) * IN_DIM);
            f32x2 aX = {0.f, 0.f}, aY = {0.f, 0.f};
            #pragma unroll
            for (int k = 0; k < 5; k++) {
                f32x4 u = xv0[k];
                pkfma(aX, wp[2 * k], u.lo); pkfma(aX, wp[2 * k + 1], u.hi);
            }
            #pragma unroll
            for (int k = 0; k < 5; k++) {
                f32x4 u = xv1[k];
                pkfma(aY, wp[2 * k], u.lo); pkfma(aY, wp[2 * k + 1], u.hi);
            }
            const float h0 = aX.x + aX.y + biasr, h1v = aY.x + aY.y + biasr;
            if (t < 2) { sm[t * KP2 + pj] = h0; sm[t * KP2 + KP + pj] = h1v; }
            else       { xst.x = h0; xst.y = h1v; }
        }
    }
    __syncthreads();

    for (int s = 0; s < T_SEQ + 3; ++s) {
        const int p = s & 1, pm = p ^ 1, q3 = s % 3;

        if (tid < 600) {                 // unified gate path (branch-free dot)
            const int vX  = q3 * KP2;
            const int vH1 = H1 + pm * KP2;
            const int vH2 = H2 + p  * KP2;
            const int vH3 = H3 + pm * KP2;
            const int offA = (cA == 0) ? vX  : (cA == 1 ? vH1 : vH2);
            const int offB = (cB == 1) ? vH1 : (cB == 2 ? vH2 : vH3);
            const f32x4* A0 = (const f32x4*)(sm + offA);
            const f32x4* A1 = (const f32x4*)(sm + offA + KP);
            const f32x4* B0 = (const f32x4*)(sm + offB);
            const f32x4* B1 = (const f32x4*)(sm + offB + KP);
            f32x2 ac0 = {0.f, 0.f}, ac1 = {0.f, 0.f};
            f32x2 ac2 = {0.f, 0.f}, ac3 = {0.f, 0.f};
            #pragma unroll
            for (int k = 0; k < 13; k++) {
                f32x4 u0 = A0[k], u1 = A1[k];
                pkfma(ac0, wp[2 * k],     u0.lo);
                pkfma(ac1, wp[2 * k + 1], u0.hi);
                pkfma(ac2, wp[2 * k],     u1.lo);
                pkfma(ac3, wp[2 * k + 1], u1.hi);
            }
            #pragma unroll
            for (int k = 0; k < 13; k++) {
                f32x4 u0 = B0[k], u1 = B1[k];
                pkfma(ac0, wp[26 + 2 * k],     u0.lo);
                pkfma(ac1, wp[26 + 2 * k + 1], u0.hi);
                pkfma(ac2, wp[26 + 2 * k],     u1.lo);
                pkfma(ac3, wp[26 + 2 * k + 1], u1.hi);
            }
            const float sx = ac0.x + ac0.y + ac1.x + ac1.y + biasr;
            const float sy = ac2.x + ac2.y + ac3.x + ac3.y + biasr;
            const bool valid = alive && ((unsigned)(s - dly) < (unsigned)T_SEQ);
            f32x2 a;
            a.x = valid ? fmaf(a2, sigm(a2 * sx), cc) : 0.f;
            a.y = valid ? fmaf(a2, sigm(a2 * sy), cc) : 0.f;

            // in-wave combine: xor1 -> product -> xor2 -> (xor4 for L23)
            f32x2 t1 = swz2<0x80B1>(a);      // partner gate
            f32x2 v2 = a * t1;               // i*g products in i-lanes
            f32x2 t2 = swz2<0x804E>(v2);     // P -> f-lane (and P3 -> o3-lane)
            f32x2 t3 = {0.f, 0.f};
            if (tid < 400) t3 = swz2<0x101F>(t2);  // P3 -> f2-lane

            if (comb == 1) {                 // L1 f-lane: a=f, t1=o, t2=P
                c1.x = fmaf(a.x, c1.x, t2.x);
                c1.y = fmaf(a.y, c1.y, t2.y);
                sm[H1 + p * KP2 + j]      = t1.x * tanh_f(c1.x);
                sm[H1 + p * KP2 + KP + j] = t1.y * tanh_f(c1.y);
            } else if (comb == 2) {          // L2 f-lane: a=f2,t1=o2,t2=P2,t3=P3
                const float cx = fmaf(a.x, t3.x, t2.x);
                const float cy = fmaf(a.y, t3.y, t2.y);
                sm[H2 + pm * KP2 + j]      = t1.x * tanh_f(cx);
                sm[H2 + pm * KP2 + KP + j] = t1.y * tanh_f(cy);
            } else if (comb == 3) {          // L3 o-lane: a=o3, t2=P3 (c3==0)
                sm[H3 + p * KP2 + j]      = a.x * tanh_f(t2.x);
                sm[H3 + p * KP2 + KP + j] = a.y * tanh_f(t2.y);
            }
        } else if (tid >= 640 && tid < 656) {          // out(t = s-3)
            if (s >= 3) {
                const int t = s - 3;
                const f32x4* hv = (const f32x4*)(sm + H3 + pm * KP2 + ob * KP);
                f32x2 e0 = {0.f, 0.f}, e1 = {0.f, 0.f};
                #pragma unroll
                for (int k = 0; k < 13; k++) {
                    f32x4 u = hv[k];
                    pkfma(e0, wp[2 * k],     u.lo);
                    pkfma(e1, wp[2 * k + 1], u.hi);
                }
                out[((size_t)(b0 + ob) * T_SEQ + t) * OUT_DIM + ok]
                    = e0.x + e0.y + e1.x + e1.y + biasr;
            }
        } else if (tid >= 704 && tid < 754) {          // prefetch
            const int sl = (s + 2) % 3;
            if (s + 2 < T_SEQ) {           // commit staged hid(s+2)
                sm[sl * KP2 + pj]      = xst.x;
                sm[sl * KP2 + KP + pj] = xst.y;
            }
            if (s + 3 < T_SEQ) {           // compute hid(s+3)
                const f32x4* xv0 = (const f32x4*)
                    (x + ((size_t)b0 * T_SEQ + (s + 3)) * IN_DIM);
                const f32x4* xv1 = (const f32x4*)
                    (x + ((size_t)(b0 + 1) * T_SEQ + (s + 3)) * IN_DIM);
                f32x2 aX = {0.f, 0.f}, aY = {0.f, 0.f};
                #pragma unroll
                for (int k = 0; k < 5; k++) {
                    f32x4 u = xv0[k];
                    pkfma(aX, wp[2 * k], u.lo); pkfma(aX, wp[2 * k + 1], u.hi);
                }
                #pragma unroll
                for (int k = 0; k < 5; k++) {
                    f32x4 u = xv1[k];
                    pkfma(aY, wp[2 * k], u.lo); pkfma(aY, wp[2 * k + 1], u.hi);
                }
                xst.x = aX.x + aX.y + biasr;
                xst.y = aY.x + aY.y + biasr;
            }
        }
        __syncthreads();
    }
}

extern "C" void kernel_launch(void* const* d_in, const int* in_sizes, int n_in,
                              void* d_out, int out_size, void* d_ws, size_t ws_size,
                              hipStream_t stream) {
    const float* x    = (const float*)d_in[0];
    const float* W1   = (const float*)d_in[1];
    const float* b1   = (const float*)d_in[2];
    const float* Wih1 = (const float*)d_in[3];
    const float* Whh1 = (const float*)d_in[4];
    const float* bih1 = (const float*)d_in[5];
    const float* bhh1 = (const float*)d_in[6];
    const float* Wih2 = (const float*)d_in[7];
    const float* Whh2 = (const float*)d_in[8];
    const float* bih2 = (const float*)d_in[9];
    const float* bhh2 = (const float*)d_in[10];
    const float* Wih3 = (const float*)d_in[11];
    const float* Whh3 = (const float*)d_in[12];
    const float* bih3 = (const float*)d_in[13];
    const float* bhh3 = (const float*)d_in[14];
    const float* W2   = (const float*)d_in[15];
    const float* b2   = (const float*)d_in[16];
    float* out = (float*)d_out;

    dim3 grid(256), block(768);
    lstm_net_kernel<<<grid, block, 0, stream>>>(
        x, W1, b1, Wih1, Whh1, bih1, bhh1, Wih2, Whh2, bih2, bhh2,
        Wih3, Whh3, bih3, bhh3, W2, b2, out);
}

// Round 3
// 1686.090 us; speedup vs baseline: 1.2601x; 1.0315x over previous
//
#include <hip/hip_runtime.h>

// LSTM net: linear1(20->50) -> 3x LSTMCell(50) (reference's buggy c-flow)
//   -> linear2(50->8).  B=512, T=1024.
//
// 256 blocks x 704 threads (11 waves), 1 block/CU, 2 batch elems/block.
// Single barrier per timestep. Quad-split-k gate compute:
//   each unit's 4 gates computed by a 4-lane quad; lane r holds ALL 4 gate
//   rows over k-chunk r (26 of the 104-dim [in;h] concat) -> 13 ds_read_b128
//   per lane (was 52), weights stay ~104 VGPRs (launch_bounds(704,2) gives a
//   256-reg cap so they stay ARCH VGPRs - round-2's 170-cap AGPR-parking
//   cost ~104 v_accvgpr_read per lane per step).
// Quad reduction = DPP quad_perm butterfly (VALU pipe, not LDS).
// L3->L2 cell-bug handoff (c2 <- i3*g3 same step) via one ds_swizzle xor4
// within the octet [L2 quad | L3 quad].
// linear1 folded into L1 gate weights: Wfold = Wih1@W1 (prologue), so the
// x-stage just copies raw x(t) (20 dims) into a 3-slot LDS ring.
//
// Lane map: tid 0-399 octets (unit=tid>>3): [L2 chunks 0-3 | L3 chunks 0-3]
//           tid 400-599 L1 quads (unit=(tid-400)>>2), 600-639 dummies
//           tid 640-647 out-proj (ok=tid-640, both batches via pk)
//           tid 648-667 x-stage (k=tid-648)
// Step s: L1 t=s, L2 t=s-1, L3 t=s-2, out t=s-3, stage commits x(s+2).

#define T_SEQ 1024
#define HID   50
#define IN_DIM 20
#define OUT_DIM 8

typedef float f32x2 __attribute__((ext_vector_type(2)));
typedef float f32x4 __attribute__((ext_vector_type(4)));

// d += broadcast(w.lo) * u   /   d += broadcast(w.hi) * u   (VOP3P op_sel)
__device__ __forceinline__ void pkfma_lo(f32x2& d, f32x2 w, f32x2 u) {
    asm("v_pk_fma_f32 %0, %1, %2, %0 op_sel:[0,0,0] op_sel_hi:[0,1,1]"
        : "+v"(d) : "v"(w), "v"(u));
}
__device__ __forceinline__ void pkfma_hi(f32x2& d, f32x2 w, f32x2 u) {
    asm("v_pk_fma_f32 %0, %1, %2, %0 op_sel:[1,0,0] op_sel_hi:[1,1,1]"
        : "+v"(d) : "v"(w), "v"(u));
}
__device__ __forceinline__ float sigm(float x) {
    return __builtin_amdgcn_rcpf(1.0f + __expf(-x));
}
__device__ __forceinline__ float tanh_f(float x) {
    return fmaf(2.0f, sigm(2.0f * x), -1.0f);
}
// quad_perm DPP exchange+self (VALU pipe): returns value from lane^1 / ^2
template <int CTRL>
__device__ __forceinline__ f32x2 dpp2(f32x2 v) {
    f32x2 r;
    r.x = __int_as_float(__builtin_amdgcn_mov_dpp(__float_as_int(v.x), CTRL, 0xF, 0xF, true));
    r.y = __int_as_float(__builtin_amdgcn_mov_dpp(__float_as_int(v.y), CTRL, 0xF, 0xF, true));
    return r;
}
__device__ __forceinline__ f32x2 swzx4(f32x2 v) {   // lane ^ 4 (bit-mode)
    f32x2 r;
    r.x = __int_as_float(__builtin_amdgcn_ds_swizzle(__float_as_int(v.x), 0x101F));
    r.y = __int_as_float(__builtin_amdgcn_ds_swizzle(__float_as_int(v.y), 0x101F));
    return r;
}

__global__ __launch_bounds__(704, 2) void lstm_net_kernel(
    const float* __restrict__ x,
    const float* __restrict__ W1,   const float* __restrict__ b1,
    const float* __restrict__ Wih1, const float* __restrict__ Whh1,
    const float* __restrict__ bih1, const float* __restrict__ bhh1,
    const float* __restrict__ Wih2, const float* __restrict__ Whh2,
    const float* __restrict__ bih2, const float* __restrict__ bhh2,
    const float* __restrict__ Wih3, const float* __restrict__ Whh3,
    const float* __restrict__ bih3, const float* __restrict__ bhh3,
    const float* __restrict__ W2,   const float* __restrict__ b2,
    float* __restrict__ out)
{
    // all LDS in f32x2 {batch0, batch1} units
    __shared__ __align__(16) f32x2 sm2[390];
    f32x2* xr  = sm2;          // [3][26] raw-x ring (20 used, pads 0)
    f32x2* h1b = sm2 + 78;     // [2][52] (50 used, pads 0)
    f32x2* h2b = sm2 + 182;    // [2][52]
    f32x2* h3b = sm2 + 286;    // [2][52] (ends at 390)

    const int tid = threadIdx.x;
    const int b0  = blockIdx.x * 2;

    for (int i = tid; i < 390; i += 704) sm2[i] = (f32x2){0.f, 0.f};
    __syncthreads();

    // ---- roles ----
    f32x2 wv[52];                       // 4 gates x 13 weight k-pairs
    float bias4[4] = {0.f, 0.f, 0.f, 0.f};
    int   bsel = 0, boff = 0;           // operand base select / offset
    bool  isGate = false, isL1 = false, isL2 = false, isL3 = false, wr = false;
    int   unit = 0, ok = 0, sk = 0;
    f32x2 c1 = {0.f, 0.f}, xstg = {0.f, 0.f};

    #pragma unroll
    for (int i = 0; i < 52; i++) wv[i] = (f32x2){0.f, 0.f};

    if (tid < 640) {
        isGate = true;
        int r, layer;
        if (tid < 400) {
            unit = tid >> 3; const int r8 = tid & 7;
            isL2 = (r8 < 4); isL3 = !isL2; r = r8 & 3;
            layer = isL2 ? 2 : 3;
            wr = (r8 == 0) || (r8 == 4);
        } else {
            unit = (tid - 400) >> 2; r = tid & 3; isL1 = true; layer = 1;
            wr = ((tid & 3) == 0) && (unit < 50);
        }
        if (layer == 2)      { bsel = (r < 2) ? 1 : 2; boff = 26 * (r & 1); }
        else if (layer == 3) { bsel = (r < 2) ? 2 : 3; boff = 26 * (r & 1); }
        else                 { bsel = (r == 0) ? 0 : 1; boff = (r == 0) ? 0 : 18 * (r - 1); }

        if (unit < 50) {
            const int row[4] = {unit, 50 + unit, 100 + unit, 150 + unit}; // i,f,g,o
            if (layer >= 2) {
                const float* src = (layer == 2) ? ((r < 2) ? Wih2 : Whh2)
                                                : ((r < 2) ? Wih3 : Whh3);
                const float* bi = (layer == 2) ? bih2 : bih3;
                const float* bh = (layer == 2) ? bhh2 : bhh3;
                #pragma unroll
                for (int m = 0; m < 4; m++) {
                    if (layer == 3 && m == 1) continue;   // f3 dead (c3 == 0)
                    bias4[m] = bi[row[m]] + bh[row[m]];
                    #pragma unroll
                    for (int i = 0; i < 13; i++) {
                        const int e0 = 26 * (r & 1) + 2 * i, e1 = e0 + 1;
                        float w0 = (e0 < 50) ? src[row[m] * 50 + e0] : 0.f;
                        float w1 = (e1 < 50) ? src[row[m] * 50 + e1] : 0.f;
                        wv[m * 13 + i] = (f32x2){w0, w1};
                    }
                }
            } else {  // L1: fold linear1 into gate weights
                #pragma unroll
                for (int m = 0; m < 4; m++) {
                    float bs = bih1[row[m]] + bhh1[row[m]];
                    for (int j2 = 0; j2 < 50; j2++)
                        bs = fmaf(Wih1[row[m] * 50 + j2], b1[j2], bs);
                    bias4[m] = bs;
                }
                if (r == 0) {           // x-chunk: Wfold = Wih1 @ W1
                    #pragma unroll
                    for (int m = 0; m < 4; m++) {
                        float a20[20];
                        #pragma unroll
                        for (int k = 0; k < 20; k++) a20[k] = 0.f;
                        for (int j2 = 0; j2 < 50; j2++) {
                            const float a = Wih1[row[m] * 50 + j2];
                            const float* w1r = W1 + j2 * 20;
                            #pragma unroll
                            for (int k = 0; k < 20; k++)
                                a20[k] = fmaf(a, w1r[k], a20[k]);
                        }
                        #pragma unroll
                        for (int i = 0; i < 10; i++)
                            wv[m * 13 + i] = (f32x2){a20[2 * i], a20[2 * i + 1]};
                    }
                } else {                // h1-chunks: Whh1, disjoint coverage
                    const int off = 18 * (r - 1);
                    const int ecap = (r == 3) ? 14 : 18;
                    #pragma unroll
                    for (int m = 0; m < 4; m++)
                    #pragma unroll
                    for (int i = 0; i < 13; i++) {
                        const int e0 = 2 * i, e1 = e0 + 1;
                        float w0 = (e0 < ecap) ? Whh1[row[m] * 50 + off + e0] : 0.f;
                        float w1 = (e1 < ecap) ? Whh1[row[m] * 50 + off + e1] : 0.f;
                        wv[m * 13 + i] = (f32x2){w0, w1};
                    }
                }
            }
        }
    } else if (tid < 648) {             // out-proj
        ok = tid - 640;
        #pragma unroll
        for (int i = 0; i < 26; i++) {
            const int e0 = 2 * i, e1 = e0 + 1;
            float w0 = (e0 < 50) ? W2[ok * 50 + e0] : 0.f;
            float w1 = (e1 < 50) ? W2[ok * 50 + e1] : 0.f;
            wv[i] = (f32x2){w0, w1};
        }
        bias4[0] = b2[ok];
    } else if (tid < 668) {             // x-stage
        sk = tid - 648;
        #pragma unroll
        for (int t = 0; t < 3; t++) {
            f32x2 v;
            v.x = x[((size_t)b0 * T_SEQ + t) * IN_DIM + sk];
            v.y = x[((size_t)(b0 + 1) * T_SEQ + t) * IN_DIM + sk];
            if (t < 2) xr[t * 26 + sk] = v; else xstg = v;
        }
    }
    __syncthreads();

    for (int s = 0; s < T_SEQ + 3; ++s) {
        const int p = s & 1, pm = p ^ 1, q3 = s % 3;

        if (isGate) {
            const f32x2* base =
                (bsel == 0) ? (xr + q3 * 26) :
                (bsel == 1) ? (h1b + pm * 52) :
                (bsel == 2) ? (h2b + p * 52) : (h3b + pm * 52);
            base += boff;
            const f32x4* B4 = (const f32x4*)base;
            f32x2 a0 = {0.f,0.f}, a1 = {0.f,0.f}, a2 = {0.f,0.f}, a3 = {0.f,0.f};
            #pragma unroll
            for (int i = 0; i < 13; i++) {
                const f32x4 u = B4[i];           // operand elems 2i, 2i+1
                const f32x2 ul = {u.x, u.y}, uh = {u.z, u.w};
                pkfma_lo(a0, wv[i],      ul); pkfma_hi(a0, wv[i],      uh);
                pkfma_lo(a1, wv[13 + i], ul); pkfma_hi(a1, wv[13 + i], uh);
                pkfma_lo(a2, wv[26 + i], ul); pkfma_hi(a2, wv[26 + i], uh);
                pkfma_lo(a3, wv[39 + i], ul); pkfma_hi(a3, wv[39 + i], uh);
            }
            // quad allreduce (DPP, VALU pipe): every lane gets all 4 totals
            a0 += dpp2<0xB1>(a0); a0 += dpp2<0x4E>(a0);
            a1 += dpp2<0xB1>(a1); a1 += dpp2<0x4E>(a1);
            a2 += dpp2<0xB1>(a2); a2 += dpp2<0x4E>(a2);
            a3 += dpp2<0xB1>(a3); a3 += dpp2<0x4E>(a3);

            f32x2 ii = {sigm(a0.x + bias4[0]),   sigm(a0.y + bias4[0])};
            f32x2 ff = {sigm(a1.x + bias4[1]),   sigm(a1.y + bias4[1])};
            f32x2 gg = {tanh_f(a2.x + bias4[2]), tanh_f(a2.y + bias4[2])};
            f32x2 oo = {sigm(a3.x + bias4[3]),   sigm(a3.y + bias4[3])};
            f32x2 ig = ii * gg;

            const bool valid3 = (s >= 2) && (s < T_SEQ + 2);
            f32x2 ps = ig;
            if (isL3 && !valid3) ps = (f32x2){0.f, 0.f};
            const f32x2 pr = swzx4(ps);          // L2 lanes receive P3 = c2_prev

            if (isL1) {
                if (s < T_SEQ) {
                    c1.x = fmaf(ff.x, c1.x, ig.x);
                    c1.y = fmaf(ff.y, c1.y, ig.y);
                    if (wr) {
                        f32x2 h;
                        h.x = oo.x * tanh_f(c1.x); h.y = oo.y * tanh_f(c1.y);
                        h1b[p * 52 + unit] = h;
                    }
                }
            } else if (isL2) {
                if (s >= 1 && s <= T_SEQ) {
                    f32x2 c2;
                    c2.x = fmaf(ff.x, pr.x, ig.x);
                    c2.y = fmaf(ff.y, pr.y, ig.y);
                    if (wr) {
                        f32x2 h;
                        h.x = oo.x * tanh_f(c2.x); h.y = oo.y * tanh_f(c2.y);
                        h2b[pm * 52 + unit] = h;
                    }
                }
            } else {  // L3 (c3 == 0: cell = i3*g3)
                if (valid3 && wr) {
                    f32x2 h;
                    h.x = oo.x * tanh_f(ig.x); h.y = oo.y * tanh_f(ig.y);
                    h3b[p * 52 + unit] = h;
                }
            }
        } else if (tid < 648) {                  // out(t = s-3)
            if (s >= 3) {
                const f32x4* H4 = (const f32x4*)(h3b + pm * 52);
                f32x2 acc = {0.f, 0.f};
                #pragma unroll
                for (int i = 0; i < 26; i++) {
                    const f32x4 u = H4[i];
                    const f32x2 ul = {u.x, u.y}, uh = {u.z, u.w};
                    pkfma_lo(acc, wv[i], ul);
                    pkfma_hi(acc, wv[i], uh);
                }
                const int t = s - 3;
                out[((size_t)b0 * T_SEQ + t) * OUT_DIM + ok]       = acc.x + bias4[0];
                out[((size_t)(b0 + 1) * T_SEQ + t) * OUT_DIM + ok] = acc.y + bias4[0];
            }
        } else if (tid < 668) {                  // x-stage
            if (s + 2 < T_SEQ) xr[((s + 2) % 3) * 26 + sk] = xstg;
            if (s + 3 < T_SEQ) {
                xstg.x = x[((size_t)b0 * T_SEQ + (s + 3)) * IN_DIM + sk];
                xstg.y = x[((size_t)(b0 + 1) * T_SEQ + (s + 3)) * IN_DIM + sk];
            }
        }
        __syncthreads();
    }
}

extern "C" void kernel_launch(void* const* d_in, const int* in_sizes, int n_in,
                              void* d_out, int out_size, void* d_ws, size_t ws_size,
                              hipStream_t stream) {
    const float* x    = (const float*)d_in[0];
    const float* W1   = (const float*)d_in[1];
    const float* b1   = (const float*)d_in[2];
    const float* Wih1 = (const float*)d_in[3];
    const float* Whh1 = (const float*)d_in[4];
    const float* bih1 = (const float*)d_in[5];
    const float* bhh1 = (const float*)d_in[6];
    const float* Wih2 = (const float*)d_in[7];
    const float* Whh2 = (const float*)d_in[8];
    const float* bih2 = (const float*)d_in[9];
    const float* bhh2 = (const float*)d_in[10];
    const float* Wih3 = (const float*)d_in[11];
    const float* Whh3 = (const float*)d_in[12];
    const float* bih3 = (const float*)d_in[13];
    const float* bhh3 = (const float*)d_in[14];
    const float* W2   = (const float*)d_in[15];
    const float* b2   = (const float*)d_in[16];
    float* out = (float*)d_out;

    dim3 grid(256), block(704);
    lstm_net_kernel<<<grid, block, 0, stream>>>(
        x, W1, b1, Wih1, Whh1, bih1, bhh1, Wih2, Whh2, bih2, bhh2,
        Wih3, Whh3, bih3, bhh3, W2, b2, out);
}